// Round 18
// baseline (272.420 us; speedup 1.0000x reference)
//
#include <hip/hip_runtime.h>

#define NNODES 50000
#define NEDGES 600000
#define NGRAPHS 64
#define BN_EPS 1e-5f
#define NB1 ((NNODES + 255) / 256)   // 196 node-blocks
#define PPG 16                        // pooling parts per graph
#define GEMM_BLOCKS ((NNODES + 127) / 128)   // 391
#define NOWN 8                        // owner ranges (dst stream = NOWN x 2.4MB)
#define RANGE 6250                    // NNODES / NOWN (exact)
#define SEG 16                        // edge segments
#define SEGI4 (NEDGES / SEG / 4)      // 9375 int4 per segment
#define HIST_BLOCKS (NOWN * SEG)      // 128

// ---------------- fp32 GEMM tile body: C[M,128] = A[M,128] @ W[128,128] ----------------
// 128x128 tile per block, 512 threads, 4x8 micro-tile, BK=16 (20.7KB LDS).

__device__ __forceinline__ void gemm_tile(const float* __restrict__ A,
        const float* __restrict__ W, float* __restrict__ C, int block) {
    __shared__ float a_lds[16][132];
    __shared__ float w_lds[16][192];
    const int tid = threadIdx.x;
    const int row0 = block * 128;
    const int tx = tid & 15;
    const int ty = tid >> 4;
    float acc[4][8];
#pragma unroll
    for (int i = 0; i < 4; ++i)
#pragma unroll
        for (int j = 0; j < 8; ++j) acc[i][j] = 0.f;

    for (int kc = 0; kc < 128; kc += 16) {
        {   // stage A chunk (transposed): 512 float4, 1 per thread
            int r = tid >> 2;
            int k4 = (tid & 3) << 2;
            int grow = row0 + r;
            float4 v = make_float4(0.f, 0.f, 0.f, 0.f);
            if (grow < NNODES) v = *(const float4*)(A + (size_t)grow * 128 + kc + k4);
            a_lds[k4 + 0][r] = v.x; a_lds[k4 + 1][r] = v.y;
            a_lds[k4 + 2][r] = v.z; a_lds[k4 + 3][r] = v.w;
        }
        {   // stage W chunk (swizzled): 512 float4, 1 per thread
            int kk = tid >> 5;
            int c4 = tid & 31;
            float4 v = *(const float4*)(W + (size_t)(kc + kk) * 128 + c4 * 4);
            int sw = 12 * (c4 >> 1) + ((c4 & 1) << 2);
            *(float4*)&w_lds[kk][sw] = v;
        }
        __syncthreads();
#pragma unroll
        for (int k = 0; k < 16; ++k) {
            float a[4], b[8];
            *(float4*)&a[0] = *(const float4*)&a_lds[k][ty * 4];
            *(float4*)&b[0] = *(const float4*)&w_lds[k][tx * 12];
            *(float4*)&b[4] = *(const float4*)&w_lds[k][tx * 12 + 4];
#pragma unroll
            for (int i = 0; i < 4; ++i)
#pragma unroll
                for (int j = 0; j < 8; ++j)
                    acc[i][j] = fmaf(a[i], b[j], acc[i][j]);
        }
        __syncthreads();
    }
#pragma unroll
    for (int i = 0; i < 4; ++i) {
        int grow = row0 + ty * 4 + i;
        if (grow < NNODES) {
            float4 v0 = make_float4(acc[i][0], acc[i][1], acc[i][2], acc[i][3]);
            float4 v1 = make_float4(acc[i][4], acc[i][5], acc[i][6], acc[i][7]);
            *(float4*)(C + (size_t)grow * 128 + tx * 8) = v0;
            *(float4*)(C + (size_t)grow * 128 + tx * 8 + 4) = v1;
        }
    }
}

// fused: GEMM1 blocks first, then 128 hist blocks backfill. Hist = segmented
// owner-computes COUNT histogram (LDS only), NOWN=8.
__global__ __launch_bounds__(512) void k_gemm1_hist(const float* __restrict__ A,
        const float* __restrict__ W, float* __restrict__ C,
        const int* __restrict__ dst, int* __restrict__ cnt_seg) {
    if (blockIdx.x >= GEMM_BLOCKS) {
        __shared__ int lh[RANGE];
        int t = threadIdx.x;
        int hb = blockIdx.x - GEMM_BLOCKS;
        int own = hb & (NOWN - 1);
        int seg = hb >> 3;
        int lo = own * RANGE;
        for (int i = t; i < RANGE; i += 512) lh[i] = 0;
        __syncthreads();
        const int4* d4 = (const int4*)dst;
        int q1 = (seg + 1) * SEGI4;
        for (int q = seg * SEGI4 + t; q < q1; q += 512) {
            int4 v = d4[q];
            unsigned a0 = (unsigned)(v.x - lo);
            unsigned a1 = (unsigned)(v.y - lo);
            unsigned a2 = (unsigned)(v.z - lo);
            unsigned a3 = (unsigned)(v.w - lo);
            if (a0 < (unsigned)RANGE) atomicAdd(&lh[a0], 1);
            if (a1 < (unsigned)RANGE) atomicAdd(&lh[a1], 1);
            if (a2 < (unsigned)RANGE) atomicAdd(&lh[a2], 1);
            if (a3 < (unsigned)RANGE) atomicAdd(&lh[a3], 1);
        }
        __syncthreads();
        for (int i = t; i < RANGE; i += 512) cnt_seg[(size_t)seg * NNODES + lo + i] = lh[i];
        return;
    }
    gemm_tile(A, W, C, blockIdx.x);
}

// ---------------- scan (node total = sum of 16 per-seg counts) ----------------

__global__ __launch_bounds__(256) void k_scan1(const int* __restrict__ cnt_seg,
        int* __restrict__ excl, int* __restrict__ bsum) {
    __shared__ int sh[256];
    int b = blockIdx.x, t = threadIdx.x;
    int idx = b * 256 + t;
    int v = 0;
    if (idx < NNODES) {
#pragma unroll
        for (int s = 0; s < SEG; ++s) v += cnt_seg[(size_t)s * NNODES + idx];
    }
    sh[t] = v;
    __syncthreads();
#pragma unroll
    for (int off = 1; off < 256; off <<= 1) {
        int x = (t >= off) ? sh[t - off] : 0;
        __syncthreads();
        sh[t] += x;
        __syncthreads();
    }
    if (idx < NNODES) excl[idx] = sh[t] - v;
    if (t == 255) bsum[b] = sh[255];
}

// fused scan2+scan3+base: each block reduces raw bsum[0..b-1] in LDS for its
// prefix, then emits row_start and per-(node,seg) slot bases in one pass.
__global__ __launch_bounds__(256) void k_scan3base(const int* __restrict__ excl,
        const int* __restrict__ bsum, const int* __restrict__ cnt_seg,
        int* __restrict__ row_start, int* __restrict__ base) {
    __shared__ int sh[256];
    int b = blockIdx.x, t = threadIdx.x;
    sh[t] = (t < b) ? bsum[t] : 0;   // b <= 195 < NB1 <= 256
    __syncthreads();
#pragma unroll
    for (int off = 128; off > 0; off >>= 1) {
        if (t < off) sh[t] += sh[t + off];
        __syncthreads();
    }
    int prefix = sh[0];
    int idx = b * 256 + t;
    if (idx >= NNODES) return;
    int rs = excl[idx] + prefix;
    row_start[idx] = rs;
    if (idx == 0) row_start[NNODES] = NEDGES;
    int run = rs;
#pragma unroll
    for (int s = 0; s < SEG; ++s) {
        int c = cnt_seg[(size_t)s * NNODES + idx];
        base[(size_t)s * NNODES + idx] = run;
        run += c;
    }
}

// ---------------- placement: segmented re-stream (vectorized), LDS tickets ------

__global__ __launch_bounds__(512) void k_place_seg(const int* __restrict__ dst,
        const int* __restrict__ src, const float* __restrict__ ew,
        const int* __restrict__ base, int2* __restrict__ csr_pk) {
    __shared__ int lh[RANGE];
    int t = threadIdx.x;
    int own = blockIdx.x & (NOWN - 1);
    int seg = blockIdx.x >> 3;
    int lo = own * RANGE;
    for (int i = t; i < RANGE; i += 512) lh[i] = 0;
    __syncthreads();
    const int4* d4 = (const int4*)dst;
    const int4* s4 = (const int4*)src;
    const float4* w4 = (const float4*)ew;
    int q1 = (seg + 1) * SEGI4;
    for (int q = seg * SEGI4 + t; q < q1; q += 512) {
        int4 v = d4[q];
        int4 s = s4[q];
        float4 w = w4[q];
        unsigned a0 = (unsigned)(v.x - lo);
        unsigned a1 = (unsigned)(v.y - lo);
        unsigned a2 = (unsigned)(v.z - lo);
        unsigned a3 = (unsigned)(v.w - lo);
        if (a0 < (unsigned)RANGE) {
            int tk = atomicAdd(&lh[a0], 1);
            csr_pk[base[(size_t)seg * NNODES + v.x] + tk] = make_int2(s.x, __float_as_int(w.x));
        }
        if (a1 < (unsigned)RANGE) {
            int tk = atomicAdd(&lh[a1], 1);
            csr_pk[base[(size_t)seg * NNODES + v.y] + tk] = make_int2(s.y, __float_as_int(w.y));
        }
        if (a2 < (unsigned)RANGE) {
            int tk = atomicAdd(&lh[a2], 1);
            csr_pk[base[(size_t)seg * NNODES + v.z] + tk] = make_int2(s.z, __float_as_int(w.z));
        }
        if (a3 < (unsigned)RANGE) {
            int tk = atomicAdd(&lh[a3], 1);
            csr_pk[base[(size_t)seg * NNODES + v.w] + tk] = make_int2(s.w, __float_as_int(w.w));
        }
    }
}

// deg[i] = 1 + sum(row raw ew)  ->  dinv[i] = rsqrt(deg)
__global__ __launch_bounds__(256) void k_deg(const int* __restrict__ row_start,
        const int2* __restrict__ csr_pk, float* __restrict__ dinv) {
    int i = blockIdx.x * 256 + threadIdx.x;
    if (i >= NNODES) return;
    int e0 = row_start[i], e1 = row_start[i + 1];
    float deg = 1.f;
    for (int e = e0; e < e1; ++e) deg += __int_as_float(csr_pk[e].y);
    dinv[i] = rsqrtf(deg);
}

// ---------------- fused aggregate-1 + GEMM2 tail ----------------
// Gather phase identical to k_aggregate (norm in-flight, b1+relu), but the 8
// relu'd rows stay in LDS; the block then computes rows @ W2 -> out (= old
// k_gemm output). Summation over k ascending = same order as gemm_tile ->
// bitwise identical. W2 is L2-resident (64KB).

__global__ __launch_bounds__(256) void k_agg_gemm(const float* __restrict__ h,
        const float* __restrict__ dinv, const int* __restrict__ row_start,
        const int2* __restrict__ csr_pk, const float* __restrict__ bias,
        const float* __restrict__ W2, float* __restrict__ out) {
    __shared__ float rowbuf[8][128];
    int gtid = blockIdx.x * 256 + threadIdx.x;   // 6250 blocks exactly (50000*32/256)
    int i = gtid >> 5;
    int n = (threadIdx.x >> 5);                  // node slot in block (0..7)
    int lane = (gtid & 31) << 2;
    float di = dinv[i];
    float sw = di * di;
    float4 hv = *(const float4*)(h + (size_t)i * 128 + lane);
    float ax = sw * hv.x, ay = sw * hv.y, az = sw * hv.z, aw = sw * hv.w;
    int e = row_start[i];
    int e1 = row_start[i + 1];
    for (; e + 3 < e1; e += 4) {
        int2 p0 = csr_pk[e], p1 = csr_pk[e + 1], p2 = csr_pk[e + 2], p3 = csr_pk[e + 3];
        float d0 = dinv[p0.x], d1 = dinv[p1.x], d2 = dinv[p2.x], d3 = dinv[p3.x];
        float4 v0 = *(const float4*)(h + (size_t)p0.x * 128 + lane);
        float4 v1 = *(const float4*)(h + (size_t)p1.x * 128 + lane);
        float4 v2 = *(const float4*)(h + (size_t)p2.x * 128 + lane);
        float4 v3 = *(const float4*)(h + (size_t)p3.x * 128 + lane);
        float w0 = d0 * __int_as_float(p0.y) * di;
        float w1 = d1 * __int_as_float(p1.y) * di;
        float w2 = d2 * __int_as_float(p2.y) * di;
        float w3 = d3 * __int_as_float(p3.y) * di;
        ax = fmaf(w0, v0.x, ax); ay = fmaf(w0, v0.y, ay);
        az = fmaf(w0, v0.z, az); aw = fmaf(w0, v0.w, aw);
        ax = fmaf(w1, v1.x, ax); ay = fmaf(w1, v1.y, ay);
        az = fmaf(w1, v1.z, az); aw = fmaf(w1, v1.w, aw);
        ax = fmaf(w2, v2.x, ax); ay = fmaf(w2, v2.y, ay);
        az = fmaf(w2, v2.z, az); aw = fmaf(w2, v2.w, aw);
        ax = fmaf(w3, v3.x, ax); ay = fmaf(w3, v3.y, ay);
        az = fmaf(w3, v3.z, az); aw = fmaf(w3, v3.w, aw);
    }
    for (; e < e1; ++e) {
        int2 p0 = csr_pk[e];
        float w0 = dinv[p0.x] * __int_as_float(p0.y) * di;
        float4 v0 = *(const float4*)(h + (size_t)p0.x * 128 + lane);
        ax = fmaf(w0, v0.x, ax); ay = fmaf(w0, v0.y, ay);
        az = fmaf(w0, v0.z, az); aw = fmaf(w0, v0.w, aw);
    }
    float4 b = *(const float4*)(bias + lane);
    rowbuf[n][lane + 0] = fmaxf(ax + b.x, 0.f);
    rowbuf[n][lane + 1] = fmaxf(ay + b.y, 0.f);
    rowbuf[n][lane + 2] = fmaxf(az + b.z, 0.f);
    rowbuf[n][lane + 3] = fmaxf(aw + b.w, 0.f);
    __syncthreads();
    // GEMM tail: out[i][lane..lane+3] = sum_k rowbuf[n][k] * W2[k][lane..lane+3]
    const float4* w4 = (const float4*)W2;
    int l = (gtid & 31);
    float acc0 = 0.f, acc1 = 0.f, acc2 = 0.f, acc3 = 0.f;
    for (int k = 0; k < 128; k += 4) {
        float4 r = *(const float4*)&rowbuf[n][k];     // LDS broadcast b128
        float4 wa = w4[(k + 0) * 32 + l];
        float4 wb = w4[(k + 1) * 32 + l];
        float4 wc = w4[(k + 2) * 32 + l];
        float4 wd = w4[(k + 3) * 32 + l];
        acc0 = fmaf(r.x, wa.x, acc0); acc1 = fmaf(r.x, wa.y, acc1);
        acc2 = fmaf(r.x, wa.z, acc2); acc3 = fmaf(r.x, wa.w, acc3);
        acc0 = fmaf(r.y, wb.x, acc0); acc1 = fmaf(r.y, wb.y, acc1);
        acc2 = fmaf(r.y, wb.z, acc2); acc3 = fmaf(r.y, wb.w, acc3);
        acc0 = fmaf(r.z, wc.x, acc0); acc1 = fmaf(r.z, wc.y, acc1);
        acc2 = fmaf(r.z, wc.z, acc2); acc3 = fmaf(r.z, wc.w, acc3);
        acc0 = fmaf(r.w, wd.x, acc0); acc1 = fmaf(r.w, wd.y, acc1);
        acc2 = fmaf(r.w, wd.z, acc2); acc3 = fmaf(r.w, wd.w, acc3);
    }
    float4 o = make_float4(acc0, acc1, acc2, acc3);
    *(float4*)(out + (size_t)i * 128 + lane) = o;
}

// ---------------- plain aggregate (layer 2): out = relu(A_hat @ h + bias) -------

__global__ __launch_bounds__(256) void k_aggregate(const float* __restrict__ h,
        const float* __restrict__ dinv, const int* __restrict__ row_start,
        const int2* __restrict__ csr_pk, const float* __restrict__ bias,
        float* __restrict__ out) {
    int gtid = blockIdx.x * 256 + threadIdx.x;
    int i = gtid >> 5;
    int lane = (gtid & 31) << 2;
    if (i >= NNODES) return;
    float di = dinv[i];
    float sw = di * di;
    float4 hv = *(const float4*)(h + (size_t)i * 128 + lane);
    float ax = sw * hv.x, ay = sw * hv.y, az = sw * hv.z, aw = sw * hv.w;
    int e = row_start[i];
    int e1 = row_start[i + 1];
    for (; e + 3 < e1; e += 4) {
        int2 p0 = csr_pk[e], p1 = csr_pk[e + 1], p2 = csr_pk[e + 2], p3 = csr_pk[e + 3];
        float d0 = dinv[p0.x], d1 = dinv[p1.x], d2 = dinv[p2.x], d3 = dinv[p3.x];
        float4 v0 = *(const float4*)(h + (size_t)p0.x * 128 + lane);
        float4 v1 = *(const float4*)(h + (size_t)p1.x * 128 + lane);
        float4 v2 = *(const float4*)(h + (size_t)p2.x * 128 + lane);
        float4 v3 = *(const float4*)(h + (size_t)p3.x * 128 + lane);
        float w0 = d0 * __int_as_float(p0.y) * di;
        float w1 = d1 * __int_as_float(p1.y) * di;
        float w2 = d2 * __int_as_float(p2.y) * di;
        float w3 = d3 * __int_as_float(p3.y) * di;
        ax = fmaf(w0, v0.x, ax); ay = fmaf(w0, v0.y, ay);
        az = fmaf(w0, v0.z, az); aw = fmaf(w0, v0.w, aw);
        ax = fmaf(w1, v1.x, ax); ay = fmaf(w1, v1.y, ay);
        az = fmaf(w1, v1.z, az); aw = fmaf(w1, v1.w, aw);
        ax = fmaf(w2, v2.x, ax); ay = fmaf(w2, v2.y, ay);
        az = fmaf(w2, v2.z, az); aw = fmaf(w2, v2.w, aw);
        ax = fmaf(w3, v3.x, ax); ay = fmaf(w3, v3.y, ay);
        az = fmaf(w3, v3.z, az); aw = fmaf(w3, v3.w, aw);
    }
    for (; e < e1; ++e) {
        int2 p0 = csr_pk[e];
        float w0 = dinv[p0.x] * __int_as_float(p0.y) * di;
        float4 v0 = *(const float4*)(h + (size_t)p0.x * 128 + lane);
        ax = fmaf(w0, v0.x, ax); ay = fmaf(w0, v0.y, ay);
        az = fmaf(w0, v0.z, az); aw = fmaf(w0, v0.w, aw);
    }
    float4 b = *(const float4*)(bias + lane);
    float4 o;
    o.x = fmaxf(ax + b.x, 0.f);
    o.y = fmaxf(ay + b.y, 0.f);
    o.z = fmaxf(az + b.z, 0.f);
    o.w = fmaxf(aw + b.w, 0.f);
    *(float4*)(out + (size_t)i * 128 + lane) = o;
}

// ---------------- pooling: 2-phase deterministic partial sums ----------------

__global__ __launch_bounds__(256) void k_pool1(const float* __restrict__ h2,
        const int* __restrict__ batch, float* __restrict__ part) {
    __shared__ float sh[256];
    int g = blockIdx.x / PPG;
    int p = blockIdx.x % PPG;
    int t = threadIdx.x;
    int lo = 0, hi = NNODES;
    while (lo < hi) { int mid = (lo + hi) >> 1; if (batch[mid] < g) lo = mid + 1; else hi = mid; }
    int b0 = lo;
    lo = 0; hi = NNODES;
    int g1 = g + 1;
    while (lo < hi) { int mid = (lo + hi) >> 1; if (batch[mid] < g1) lo = mid + 1; else hi = mid; }
    int b1 = lo;

    int c = t & 127, q = t >> 7;
    float acc = 0.f;
    for (int r = b0 + p * 2 + q; r < b1; r += PPG * 2) acc += h2[(size_t)r * 128 + c];
    sh[t] = acc;
    __syncthreads();
    if (t < 128) part[((size_t)g * PPG + p) * 128 + t] = sh[t] + sh[t + 128];
}

__global__ __launch_bounds__(128) void k_pool2(const float* __restrict__ part,
        const int* __restrict__ batch, float* __restrict__ gmean) {
    int g = blockIdx.x;
    int t = threadIdx.x;
    int lo = 0, hi = NNODES;
    while (lo < hi) { int mid = (lo + hi) >> 1; if (batch[mid] < g) lo = mid + 1; else hi = mid; }
    int b0 = lo;
    lo = 0; hi = NNODES;
    int g1 = g + 1;
    while (lo < hi) { int mid = (lo + hi) >> 1; if (batch[mid] < g1) lo = mid + 1; else hi = mid; }
    int b1 = lo;
    float s = 0.f;
#pragma unroll
    for (int p = 0; p < PPG; ++p) s += part[((size_t)g * PPG + p) * 128 + t];
    float n = (float)(b1 - b0);
    gmean[g * 128 + t] = s / fmaxf(n, 1.f);
}

// ---------------- head: LDS-staged fc1 -> relu -> BN -> fc3 ----------------

__global__ __launch_bounds__(256) void k_head(const float* __restrict__ gmean,
        const float* __restrict__ fc1W, const float* __restrict__ fc1b,
        const float* __restrict__ gamma, const float* __restrict__ beta,
        const float* __restrict__ fc3W, const float* __restrict__ fc3b,
        float* __restrict__ out) {
    __shared__ float g[64][129];
    __shared__ float w[128][64];
    __shared__ float z[64][65];
    __shared__ float mu[64], isd[64];
    int t = threadIdx.x;
#pragma unroll
    for (int p = 0; p < 8; ++p) {
        int idx4 = p * 256 + t;
        int gg = idx4 >> 5;
        int c4 = (idx4 & 31) << 2;
        float4 v = *(const float4*)(gmean + gg * 128 + c4);
        *(float4*)&g[gg][c4] = v;
    }
#pragma unroll
    for (int p = 0; p < 8; ++p) {
        int idx4 = p * 256 + t;
        float4 v = *(const float4*)(fc1W + idx4 * 4);
        ((float4*)&w[0][0])[idx4] = v;
    }
    __syncthreads();
    int r = t >> 2;
    int c0 = (t & 3) * 16;
    float acc[16];
#pragma unroll
    for (int j = 0; j < 16; ++j) acc[j] = 0.f;
    for (int k = 0; k < 128; ++k) {
        float gv = g[r][k];
#pragma unroll
        for (int j = 0; j < 16; ++j) acc[j] = fmaf(gv, w[k][c0 + j], acc[j]);
    }
#pragma unroll
    for (int j = 0; j < 16; ++j)
        z[r][c0 + j] = fmaxf(acc[j] + fc1b[c0 + j], 0.f);
    __syncthreads();
    if (t < 64) {
        float m = 0.f;
        for (int rr = 0; rr < 64; ++rr) m += z[rr][t];
        m *= (1.f / 64.f);
        float v = 0.f;
        for (int rr = 0; rr < 64; ++rr) { float d = z[rr][t] - m; v = fmaf(d, d, v); }
        v *= (1.f / 64.f);
        mu[t] = m;
        isd[t] = rsqrtf(v + BN_EPS);
    }
    __syncthreads();
    if (t < 64) {
        float a2 = fc3b[0];
        for (int cc = 0; cc < 64; ++cc) {
            float zn = fmaf(gamma[cc] * (z[t][cc] - mu[cc]), isd[cc], beta[cc]);
            a2 = fmaf(zn, fc3W[cc], a2);
        }
        out[t] = a2;
    }
}

// ---------------- launch ----------------

extern "C" void kernel_launch(void* const* d_in, const int* in_sizes, int n_in,
                              void* d_out, int out_size, void* d_ws, size_t ws_size,
                              hipStream_t stream) {
    const float* x    = (const float*)d_in[0];
    const int*   ei   = (const int*)d_in[1];
    const int*   batch= (const int*)d_in[2];
    const float* ew   = (const float*)d_in[3];
    const float* W1   = (const float*)d_in[4];
    const float* b1   = (const float*)d_in[5];
    const float* W2   = (const float*)d_in[6];
    const float* b2   = (const float*)d_in[7];
    const float* fc1W = (const float*)d_in[8];
    const float* fc1b = (const float*)d_in[9];
    const float* gam  = (const float*)d_in[10];
    const float* bet  = (const float*)d_in[11];
    const float* fc3W = (const float*)d_in[12];
    const float* fc3b = (const float*)d_in[13];
    float* out = (float*)d_out;
    const int* srcp = ei;
    const int* dstp = ei + NEDGES;

    char* wsb = (char*)d_ws;
    size_t off = 0;
    auto alloc = [&](size_t bytes) {
        void* p = wsb + off;
        off = (off + bytes + 255) & ~(size_t)255;
        return p;
    };
    float* dinv      = (float*)alloc(NNODES * 4);
    int*   row_start = (int*)alloc((NNODES + 1) * 4);
    int*   cnt_seg   = (int*)alloc((size_t)SEG * NNODES * 4);
    int*   base      = (int*)alloc((size_t)SEG * NNODES * 4);
    int*   excl      = (int*)alloc(NNODES * 4);
    int*   bsum      = (int*)alloc(NB1 * 4);
    int2*  csr_pk    = (int2*)alloc((size_t)NEDGES * 8);
    float* hbuf      = (float*)alloc((size_t)NNODES * 128 * 4);
    float* abuf      = (float*)alloc((size_t)NNODES * 128 * 4);
    float* part      = (float*)alloc((size_t)NGRAPHS * PPG * 128 * 4);
    float* gmean     = (float*)alloc(NGRAPHS * 128 * 4);
    (void)ws_size; (void)in_sizes; (void)n_in; (void)out_size;

    // CSR build (segmented owner-computes, LDS atomics only) fused with GEMM1
    k_gemm1_hist<<<GEMM_BLOCKS + HIST_BLOCKS, 512, 0, stream>>>(x, W1, hbuf, dstp, cnt_seg);
    k_scan1<<<NB1, 256, 0, stream>>>(cnt_seg, excl, bsum);
    k_scan3base<<<NB1, 256, 0, stream>>>(excl, bsum, cnt_seg, row_start, base);
    k_place_seg<<<HIST_BLOCKS, 512, 0, stream>>>(dstp, srcp, ew, base, csr_pk);
    k_deg<<<NB1, 256, 0, stream>>>(row_start, csr_pk, dinv);

    // layer 1 aggregate fused with GEMM2 tail: hbuf -> abuf (= relu(agg)+b1 @ W2)
    k_agg_gemm<<<(NNODES * 32) / 256, 256, 0, stream>>>(hbuf, dinv, row_start,
                                                        csr_pk, b1, W2, abuf);
    // layer 2 aggregate (+b2, relu): abuf -> hbuf
    k_aggregate<<<(NNODES * 32 + 255) / 256, 256, 0, stream>>>(abuf, dinv, row_start,
                                                               csr_pk, b2, hbuf);
    // pool + head
    k_pool1<<<NGRAPHS * PPG, 256, 0, stream>>>(hbuf, batch, part);
    k_pool2<<<NGRAPHS, 128, 0, stream>>>(part, batch, gmean);
    k_head<<<1, 256, 0, stream>>>(gmean, fc1W, fc1b, gam, bet, fc3W, fc3b, out);
}

// Round 19
// 230.131 us; speedup vs baseline: 1.1838x; 1.1838x over previous
//
#include <hip/hip_runtime.h>

#define NNODES 50000
#define NEDGES 600000
#define NGRAPHS 64
#define BN_EPS 1e-5f
#define NB1 ((NNODES + 255) / 256)   // 196 node-blocks
#define PPG 16                        // pooling parts per graph
#define GEMM_BLOCKS ((NNODES + 127) / 128)   // 391
#define NOWN 8                        // owner ranges (dst stream = NOWN x 2.4MB)
#define RANGE 6250                    // NNODES / NOWN (exact)
#define SEG 16                        // edge segments
#define SEGI4 (NEDGES / SEG / 4)      // 9375 int4 per segment
#define HIST_BLOCKS (NOWN * SEG)      // 128

// ---------------- fp32 GEMM tile body: C[M,128] = A[M,128] @ W[128,128] ----------------
// 128x128 tile per block, 512 threads, 4x8 micro-tile, BK=16 (20.7KB LDS).

__device__ __forceinline__ void gemm_tile(const float* __restrict__ A,
        const float* __restrict__ W, float* __restrict__ C, int block) {
    __shared__ float a_lds[16][132];
    __shared__ float w_lds[16][192];
    const int tid = threadIdx.x;
    const int row0 = block * 128;
    const int tx = tid & 15;
    const int ty = tid >> 4;
    float acc[4][8];
#pragma unroll
    for (int i = 0; i < 4; ++i)
#pragma unroll
        for (int j = 0; j < 8; ++j) acc[i][j] = 0.f;

    for (int kc = 0; kc < 128; kc += 16) {
        {   // stage A chunk (transposed): 512 float4, 1 per thread
            int r = tid >> 2;
            int k4 = (tid & 3) << 2;
            int grow = row0 + r;
            float4 v = make_float4(0.f, 0.f, 0.f, 0.f);
            if (grow < NNODES) v = *(const float4*)(A + (size_t)grow * 128 + kc + k4);
            a_lds[k4 + 0][r] = v.x; a_lds[k4 + 1][r] = v.y;
            a_lds[k4 + 2][r] = v.z; a_lds[k4 + 3][r] = v.w;
        }
        {   // stage W chunk (swizzled): 512 float4, 1 per thread
            int kk = tid >> 5;
            int c4 = tid & 31;
            float4 v = *(const float4*)(W + (size_t)(kc + kk) * 128 + c4 * 4);
            int sw = 12 * (c4 >> 1) + ((c4 & 1) << 2);
            *(float4*)&w_lds[kk][sw] = v;
        }
        __syncthreads();
#pragma unroll
        for (int k = 0; k < 16; ++k) {
            float a[4], b[8];
            *(float4*)&a[0] = *(const float4*)&a_lds[k][ty * 4];
            *(float4*)&b[0] = *(const float4*)&w_lds[k][tx * 12];
            *(float4*)&b[4] = *(const float4*)&w_lds[k][tx * 12 + 4];
#pragma unroll
            for (int i = 0; i < 4; ++i)
#pragma unroll
                for (int j = 0; j < 8; ++j)
                    acc[i][j] = fmaf(a[i], b[j], acc[i][j]);
        }
        __syncthreads();
    }
#pragma unroll
    for (int i = 0; i < 4; ++i) {
        int grow = row0 + ty * 4 + i;
        if (grow < NNODES) {
            float4 v0 = make_float4(acc[i][0], acc[i][1], acc[i][2], acc[i][3]);
            float4 v1 = make_float4(acc[i][4], acc[i][5], acc[i][6], acc[i][7]);
            *(float4*)(C + (size_t)grow * 128 + tx * 8) = v0;
            *(float4*)(C + (size_t)grow * 128 + tx * 8 + 4) = v1;
        }
    }
}

// fused: GEMM1 blocks first (long, fill device early), then 128 hist blocks
// backfill. Hist = segmented owner-computes COUNT histogram (LDS only);
// NOWN=8 cuts redundant dst streaming 8x vs NOWN=64 (19.2MB vs 153.6MB).
__global__ __launch_bounds__(512) void k_gemm1_hist(const float* __restrict__ A,
        const float* __restrict__ W, float* __restrict__ C,
        const int* __restrict__ dst, int* __restrict__ cnt_seg) {
    if (blockIdx.x >= GEMM_BLOCKS) {
        __shared__ int lh[RANGE];
        int t = threadIdx.x;
        int hb = blockIdx.x - GEMM_BLOCKS;
        int own = hb & (NOWN - 1);
        int seg = hb >> 3;
        int lo = own * RANGE;
        for (int i = t; i < RANGE; i += 512) lh[i] = 0;
        __syncthreads();
        const int4* d4 = (const int4*)dst;
        int q1 = (seg + 1) * SEGI4;
        for (int q = seg * SEGI4 + t; q < q1; q += 512) {
            int4 v = d4[q];
            unsigned a0 = (unsigned)(v.x - lo);
            unsigned a1 = (unsigned)(v.y - lo);
            unsigned a2 = (unsigned)(v.z - lo);
            unsigned a3 = (unsigned)(v.w - lo);
            if (a0 < (unsigned)RANGE) atomicAdd(&lh[a0], 1);
            if (a1 < (unsigned)RANGE) atomicAdd(&lh[a1], 1);
            if (a2 < (unsigned)RANGE) atomicAdd(&lh[a2], 1);
            if (a3 < (unsigned)RANGE) atomicAdd(&lh[a3], 1);
        }
        __syncthreads();
        for (int i = t; i < RANGE; i += 512) cnt_seg[(size_t)seg * NNODES + lo + i] = lh[i];
        return;
    }
    gemm_tile(A, W, C, blockIdx.x);
}

__global__ __launch_bounds__(512) void k_gemm(const float* __restrict__ A,
        const float* __restrict__ W, float* __restrict__ C) {
    gemm_tile(A, W, C, blockIdx.x);
}

// ---------------- scan (node total = sum of 16 per-seg counts) ----------------

__global__ __launch_bounds__(256) void k_scan1(const int* __restrict__ cnt_seg,
        int* __restrict__ excl, int* __restrict__ bsum) {
    __shared__ int sh[256];
    int b = blockIdx.x, t = threadIdx.x;
    int idx = b * 256 + t;
    int v = 0;
    if (idx < NNODES) {
#pragma unroll
        for (int s = 0; s < SEG; ++s) v += cnt_seg[(size_t)s * NNODES + idx];
    }
    sh[t] = v;
    __syncthreads();
#pragma unroll
    for (int off = 1; off < 256; off <<= 1) {
        int x = (t >= off) ? sh[t - off] : 0;
        __syncthreads();
        sh[t] += x;
        __syncthreads();
    }
    if (idx < NNODES) excl[idx] = sh[t] - v;
    if (t == 255) bsum[b] = sh[255];
}

__global__ __launch_bounds__(256) void k_scan2(int* __restrict__ bsum) {
    __shared__ int sh[256];
    int t = threadIdx.x;
    int v = (t < NB1) ? bsum[t] : 0;
    sh[t] = v;
    __syncthreads();
#pragma unroll
    for (int off = 1; off < 256; off <<= 1) {
        int x = (t >= off) ? sh[t - off] : 0;
        __syncthreads();
        sh[t] += x;
        __syncthreads();
    }
    if (t < NB1) bsum[t] = sh[t] - v;
}

// fused scan3 + base: row_start and per-(node,seg) slot bases in one pass
__global__ __launch_bounds__(256) void k_scan3base(const int* __restrict__ excl,
        const int* __restrict__ bsum, const int* __restrict__ cnt_seg,
        int* __restrict__ row_start, int* __restrict__ base) {
    int b = blockIdx.x, t = threadIdx.x;
    int idx = b * 256 + t;
    if (idx >= NNODES) return;
    int rs = excl[idx] + bsum[b];
    row_start[idx] = rs;
    if (idx == 0) row_start[NNODES] = NEDGES;
    int run = rs;
#pragma unroll
    for (int s = 0; s < SEG; ++s) {
        int c = cnt_seg[(size_t)s * NNODES + idx];
        base[(size_t)s * NNODES + idx] = run;
        run += c;
    }
}

// ---------------- placement: segmented re-stream (vectorized), LDS tickets ------

__global__ __launch_bounds__(512) void k_place_seg(const int* __restrict__ dst,
        const int* __restrict__ src, const float* __restrict__ ew,
        const int* __restrict__ base, int2* __restrict__ csr_pk) {
    __shared__ int lh[RANGE];
    int t = threadIdx.x;
    int own = blockIdx.x & (NOWN - 1);
    int seg = blockIdx.x >> 3;
    int lo = own * RANGE;
    for (int i = t; i < RANGE; i += 512) lh[i] = 0;
    __syncthreads();
    const int4* d4 = (const int4*)dst;
    const int4* s4 = (const int4*)src;
    const float4* w4 = (const float4*)ew;
    int q1 = (seg + 1) * SEGI4;
    for (int q = seg * SEGI4 + t; q < q1; q += 512) {
        int4 v = d4[q];
        int4 s = s4[q];
        float4 w = w4[q];
        unsigned a0 = (unsigned)(v.x - lo);
        unsigned a1 = (unsigned)(v.y - lo);
        unsigned a2 = (unsigned)(v.z - lo);
        unsigned a3 = (unsigned)(v.w - lo);
        if (a0 < (unsigned)RANGE) {
            int tk = atomicAdd(&lh[a0], 1);
            csr_pk[base[(size_t)seg * NNODES + v.x] + tk] = make_int2(s.x, __float_as_int(w.x));
        }
        if (a1 < (unsigned)RANGE) {
            int tk = atomicAdd(&lh[a1], 1);
            csr_pk[base[(size_t)seg * NNODES + v.y] + tk] = make_int2(s.y, __float_as_int(w.y));
        }
        if (a2 < (unsigned)RANGE) {
            int tk = atomicAdd(&lh[a2], 1);
            csr_pk[base[(size_t)seg * NNODES + v.z] + tk] = make_int2(s.z, __float_as_int(w.z));
        }
        if (a3 < (unsigned)RANGE) {
            int tk = atomicAdd(&lh[a3], 1);
            csr_pk[base[(size_t)seg * NNODES + v.w] + tk] = make_int2(s.w, __float_as_int(w.w));
        }
    }
}

// deg[i] = 1 + sum(row raw ew)  ->  dinv[i] = rsqrt(deg)   (4.8MB row-sum)
__global__ __launch_bounds__(256) void k_deg(const int* __restrict__ row_start,
        const int2* __restrict__ csr_pk, float* __restrict__ dinv) {
    int i = blockIdx.x * 256 + threadIdx.x;
    if (i >= NNODES) return;
    int e0 = row_start[i], e1 = row_start[i + 1];
    float deg = 1.f;
    for (int e = e0; e < e1; ++e) deg += __int_as_float(csr_pk[e].y);
    dinv[i] = rsqrtf(deg);
}

// ---------------- GCN aggregate: out = relu(A_hat @ h + bias) ----------------
// 32 lanes per node, float4 per lane, 4-edge unrolled gather; normalization
// dinv[src]*ew*dinv[dst] in-flight (same multiply order as old k_wfill).

__global__ __launch_bounds__(256) void k_aggregate(const float* __restrict__ h,
        const float* __restrict__ dinv, const int* __restrict__ row_start,
        const int2* __restrict__ csr_pk, const float* __restrict__ bias,
        float* __restrict__ out) {
    int gtid = blockIdx.x * 256 + threadIdx.x;
    int i = gtid >> 5;
    int lane = (gtid & 31) << 2;
    if (i >= NNODES) return;
    float di = dinv[i];
    float sw = di * di;
    float4 hv = *(const float4*)(h + (size_t)i * 128 + lane);
    float ax = sw * hv.x, ay = sw * hv.y, az = sw * hv.z, aw = sw * hv.w;
    int e = row_start[i];
    int e1 = row_start[i + 1];
    for (; e + 3 < e1; e += 4) {
        int2 p0 = csr_pk[e], p1 = csr_pk[e + 1], p2 = csr_pk[e + 2], p3 = csr_pk[e + 3];
        float d0 = dinv[p0.x], d1 = dinv[p1.x], d2 = dinv[p2.x], d3 = dinv[p3.x];
        float4 v0 = *(const float4*)(h + (size_t)p0.x * 128 + lane);
        float4 v1 = *(const float4*)(h + (size_t)p1.x * 128 + lane);
        float4 v2 = *(const float4*)(h + (size_t)p2.x * 128 + lane);
        float4 v3 = *(const float4*)(h + (size_t)p3.x * 128 + lane);
        float w0 = d0 * __int_as_float(p0.y) * di;
        float w1 = d1 * __int_as_float(p1.y) * di;
        float w2 = d2 * __int_as_float(p2.y) * di;
        float w3 = d3 * __int_as_float(p3.y) * di;
        ax = fmaf(w0, v0.x, ax); ay = fmaf(w0, v0.y, ay);
        az = fmaf(w0, v0.z, az); aw = fmaf(w0, v0.w, aw);
        ax = fmaf(w1, v1.x, ax); ay = fmaf(w1, v1.y, ay);
        az = fmaf(w1, v1.z, az); aw = fmaf(w1, v1.w, aw);
        ax = fmaf(w2, v2.x, ax); ay = fmaf(w2, v2.y, ay);
        az = fmaf(w2, v2.z, az); aw = fmaf(w2, v2.w, aw);
        ax = fmaf(w3, v3.x, ax); ay = fmaf(w3, v3.y, ay);
        az = fmaf(w3, v3.z, az); aw = fmaf(w3, v3.w, aw);
    }
    for (; e < e1; ++e) {
        int2 p0 = csr_pk[e];
        float w0 = dinv[p0.x] * __int_as_float(p0.y) * di;
        float4 v0 = *(const float4*)(h + (size_t)p0.x * 128 + lane);
        ax = fmaf(w0, v0.x, ax); ay = fmaf(w0, v0.y, ay);
        az = fmaf(w0, v0.z, az); aw = fmaf(w0, v0.w, aw);
    }
    float4 b = *(const float4*)(bias + lane);
    float4 o;
    o.x = fmaxf(ax + b.x, 0.f);
    o.y = fmaxf(ay + b.y, 0.f);
    o.z = fmaxf(az + b.z, 0.f);
    o.w = fmaxf(aw + b.w, 0.f);
    *(float4*)(out + (size_t)i * 128 + lane) = o;
}

// ---------------- pooling: 2-phase deterministic partial sums ----------------

__global__ __launch_bounds__(256) void k_pool1(const float* __restrict__ h2,
        const int* __restrict__ batch, float* __restrict__ part) {
    __shared__ float sh[256];
    int g = blockIdx.x / PPG;
    int p = blockIdx.x % PPG;
    int t = threadIdx.x;
    int lo = 0, hi = NNODES;
    while (lo < hi) { int mid = (lo + hi) >> 1; if (batch[mid] < g) lo = mid + 1; else hi = mid; }
    int b0 = lo;
    lo = 0; hi = NNODES;
    int g1 = g + 1;
    while (lo < hi) { int mid = (lo + hi) >> 1; if (batch[mid] < g1) lo = mid + 1; else hi = mid; }
    int b1 = lo;

    int c = t & 127, q = t >> 7;
    float acc = 0.f;
    for (int r = b0 + p * 2 + q; r < b1; r += PPG * 2) acc += h2[(size_t)r * 128 + c];
    sh[t] = acc;
    __syncthreads();
    if (t < 128) part[((size_t)g * PPG + p) * 128 + t] = sh[t] + sh[t + 128];
}

__global__ __launch_bounds__(128) void k_pool2(const float* __restrict__ part,
        const int* __restrict__ batch, float* __restrict__ gmean) {
    int g = blockIdx.x;
    int t = threadIdx.x;
    int lo = 0, hi = NNODES;
    while (lo < hi) { int mid = (lo + hi) >> 1; if (batch[mid] < g) lo = mid + 1; else hi = mid; }
    int b0 = lo;
    lo = 0; hi = NNODES;
    int g1 = g + 1;
    while (lo < hi) { int mid = (lo + hi) >> 1; if (batch[mid] < g1) lo = mid + 1; else hi = mid; }
    int b1 = lo;
    float s = 0.f;
#pragma unroll
    for (int p = 0; p < PPG; ++p) s += part[((size_t)g * PPG + p) * 128 + t];
    float n = (float)(b1 - b0);
    gmean[g * 128 + t] = s / fmaxf(n, 1.f);
}

// ---------------- head: LDS-staged fc1 -> relu -> BN -> fc3 ----------------

__global__ __launch_bounds__(256) void k_head(const float* __restrict__ gmean,
        const float* __restrict__ fc1W, const float* __restrict__ fc1b,
        const float* __restrict__ gamma, const float* __restrict__ beta,
        const float* __restrict__ fc3W, const float* __restrict__ fc3b,
        float* __restrict__ out) {
    __shared__ float g[64][129];
    __shared__ float w[128][64];
    __shared__ float z[64][65];
    __shared__ float mu[64], isd[64];
    int t = threadIdx.x;
#pragma unroll
    for (int p = 0; p < 8; ++p) {    // stage gmean: 2048 float4
        int idx4 = p * 256 + t;
        int gg = idx4 >> 5;
        int c4 = (idx4 & 31) << 2;
        float4 v = *(const float4*)(gmean + gg * 128 + c4);
        *(float4*)&g[gg][c4] = v;
    }
#pragma unroll
    for (int p = 0; p < 8; ++p) {    // stage fc1W flat: 2048 float4
        int idx4 = p * 256 + t;
        float4 v = *(const float4*)(fc1W + idx4 * 4);
        ((float4*)&w[0][0])[idx4] = v;
    }
    __syncthreads();
    int r = t >> 2;
    int c0 = (t & 3) * 16;
    float acc[16];
#pragma unroll
    for (int j = 0; j < 16; ++j) acc[j] = 0.f;
    for (int k = 0; k < 128; ++k) {
        float gv = g[r][k];
#pragma unroll
        for (int j = 0; j < 16; ++j) acc[j] = fmaf(gv, w[k][c0 + j], acc[j]);
    }
#pragma unroll
    for (int j = 0; j < 16; ++j)
        z[r][c0 + j] = fmaxf(acc[j] + fc1b[c0 + j], 0.f);
    __syncthreads();
    if (t < 64) {
        float m = 0.f;
        for (int rr = 0; rr < 64; ++rr) m += z[rr][t];
        m *= (1.f / 64.f);
        float v = 0.f;
        for (int rr = 0; rr < 64; ++rr) { float d = z[rr][t] - m; v = fmaf(d, d, v); }
        v *= (1.f / 64.f);
        mu[t] = m;
        isd[t] = rsqrtf(v + BN_EPS);
    }
    __syncthreads();
    if (t < 64) {
        float a2 = fc3b[0];
        for (int cc = 0; cc < 64; ++cc) {
            float zn = fmaf(gamma[cc] * (z[t][cc] - mu[cc]), isd[cc], beta[cc]);
            a2 = fmaf(zn, fc3W[cc], a2);
        }
        out[t] = a2;
    }
}

// ---------------- launch ----------------

extern "C" void kernel_launch(void* const* d_in, const int* in_sizes, int n_in,
                              void* d_out, int out_size, void* d_ws, size_t ws_size,
                              hipStream_t stream) {
    const float* x    = (const float*)d_in[0];
    const int*   ei   = (const int*)d_in[1];
    const int*   batch= (const int*)d_in[2];
    const float* ew   = (const float*)d_in[3];
    const float* W1   = (const float*)d_in[4];
    const float* b1   = (const float*)d_in[5];
    const float* W2   = (const float*)d_in[6];
    const float* b2   = (const float*)d_in[7];
    const float* fc1W = (const float*)d_in[8];
    const float* fc1b = (const float*)d_in[9];
    const float* gam  = (const float*)d_in[10];
    const float* bet  = (const float*)d_in[11];
    const float* fc3W = (const float*)d_in[12];
    const float* fc3b = (const float*)d_in[13];
    float* out = (float*)d_out;
    const int* srcp = ei;
    const int* dstp = ei + NEDGES;

    char* wsb = (char*)d_ws;
    size_t off = 0;
    auto alloc = [&](size_t bytes) {
        void* p = wsb + off;
        off = (off + bytes + 255) & ~(size_t)255;
        return p;
    };
    float* dinv      = (float*)alloc(NNODES * 4);
    int*   row_start = (int*)alloc((NNODES + 1) * 4);
    int*   cnt_seg   = (int*)alloc((size_t)SEG * NNODES * 4);
    int*   base      = (int*)alloc((size_t)SEG * NNODES * 4);
    int*   excl      = (int*)alloc(NNODES * 4);
    int*   bsum      = (int*)alloc(NB1 * 4);
    int2*  csr_pk    = (int2*)alloc((size_t)NEDGES * 8);
    float* hbuf      = (float*)alloc((size_t)NNODES * 128 * 4);
    float* abuf      = (float*)alloc((size_t)NNODES * 128 * 4);
    float* part      = (float*)alloc((size_t)NGRAPHS * PPG * 128 * 4);
    float* gmean     = (float*)alloc(NGRAPHS * 128 * 4);
    (void)ws_size; (void)in_sizes; (void)n_in; (void)out_size;

    // CSR build (segmented owner-computes, LDS atomics only) fused with GEMM1
    k_gemm1_hist<<<GEMM_BLOCKS + HIST_BLOCKS, 512, 0, stream>>>(x, W1, hbuf, dstp, cnt_seg);
    k_scan1<<<NB1, 256, 0, stream>>>(cnt_seg, excl, bsum);
    k_scan2<<<1, 256, 0, stream>>>(bsum);
    k_scan3base<<<NB1, 256, 0, stream>>>(excl, bsum, cnt_seg, row_start, base);
    k_place_seg<<<HIST_BLOCKS, 512, 0, stream>>>(dstp, srcp, ew, base, csr_pk);
    k_deg<<<NB1, 256, 0, stream>>>(row_start, csr_pk, dinv);

    // layer 1 aggregate (normalization folded in)
    k_aggregate<<<(NNODES * 32 + 255) / 256, 256, 0, stream>>>(hbuf, dinv, row_start,
                                                               csr_pk, b1, abuf);
    // layer 2
    k_gemm<<<GEMM_BLOCKS, 512, 0, stream>>>(abuf, W2, hbuf);
    k_aggregate<<<(NNODES * 32 + 255) / 256, 256, 0, stream>>>(hbuf, dinv, row_start,
                                                               csr_pk, b2, abuf);
    // pool + head
    k_pool1<<<NGRAPHS * PPG, 256, 0, stream>>>(abuf, batch, part);
    k_pool2<<<NGRAPHS, 128, 0, stream>>>(part, batch, gmean);
    k_head<<<1, 256, 0, stream>>>(gmean, fc1W, fc1b, gam, bet, fc3W, fc3b, out);
}